// Round 6
// baseline (284.456 us; speedup 1.0000x reference)
//
#include <hip/hip_runtime.h>

#define B_   8
#define T_   4096
#define D_   1024
#define E_   100
#define EP_  128
#define NTOK (B_*T_)
#define TC_  8            // t-chunks in k_feat
#define KT_  (T_/TC_)     // 512

typedef short bf16x8 __attribute__((ext_vector_type(8)));
typedef float f32x4  __attribute__((ext_vector_type(4)));

__device__ __forceinline__ unsigned short f2b(float f){
    union { float f; unsigned int i; } v; v.f = f;
    unsigned int x = v.i;
    return (unsigned short)((x + 0x7fffu + ((x >> 16) & 1u)) >> 16);
}
__device__ __forceinline__ uint4 pack8(float4 a, float4 b){
    uint4 r;
    r.x = (unsigned int)f2b(a.x) | ((unsigned int)f2b(a.y) << 16);
    r.y = (unsigned int)f2b(a.z) | ((unsigned int)f2b(a.w) << 16);
    r.z = (unsigned int)f2b(b.x) | ((unsigned int)f2b(b.y) << 16);
    r.w = (unsigned int)f2b(b.z) | ((unsigned int)f2b(b.w) << 16);
    return r;
}
__device__ __forceinline__ bf16x8 pk(float4 a, float4 b){
    union { uint4 u; bf16x8 h; } c; c.u = pack8(a, b); return c.h;
}
__device__ __forceinline__ void dma16(const unsigned short* g, unsigned short* l){
    __builtin_amdgcn_global_load_lds(
        (const __attribute__((address_space(1))) unsigned int*)(const void*)g,
        (__attribute__((address_space(3))) unsigned int*)(void*)l,
        16, 0, 0);
}

// ---------------- K1: normalize centroids (fp32 in) -> cn[EP_][D_] bf16 --------
__global__ __launch_bounds__(256) void k_cnorm(const float* __restrict__ cent,
                                               unsigned short* __restrict__ cn){
    const int e = blockIdx.x, tid = threadIdx.x;
    if (e >= E_){
        ((uint2*)(cn + (size_t)e*D_))[tid] = make_uint2(0u, 0u);
        return;
    }
    float4 x = ((const float4*)(cent + (size_t)e*D_))[tid];
    float ss = x.x*x.x + x.y*x.y + x.z*x.z + x.w*x.w;
    __shared__ float red[256];
    red[tid] = ss; __syncthreads();
    for (int s = 128; s > 0; s >>= 1){ if (tid < s) red[tid] += red[tid+s]; __syncthreads(); }
    float inv = 1.0f / fmaxf(sqrtf(red[0]), 1e-12f);
    unsigned int lo = (unsigned int)f2b(x.x*inv) | ((unsigned int)f2b(x.y*inv) << 16);
    unsigned int hi = (unsigned int)f2b(x.z*inv) | ((unsigned int)f2b(x.w*inv) << 16);
    ((uint2*)(cn + (size_t)e*D_))[tid] = make_uint2(lo, hi);
}

// ---------------- K2: K-split fused prep + sim GEMM + softmax ------------------
// grid = NTOK/16 = 2048 blocks x 256 thr. Block = 16 tokens x 128 e; wave w
// owns K-quarter [w*256, w*256+256) -> 4 MFMA steps of 64. 16 waves/CU (2x r5).
// Partial C combined in LDS fp32; wave-parallel softmax; coalesced row writes.
// No barriers in the main loop (waves fully independent until epilogue).
__global__ __launch_bounds__(256) void k_sim(const float* __restrict__ tokens,
                                             const unsigned short* __restrict__ cn,
                                             float* __restrict__ out_assign,
                                             unsigned short* __restrict__ pT,
                                             float* __restrict__ wpart){
    __shared__ __align__(16) char smem[39168];
    float* simp = (float*)smem;                        // [4][16][128] fp32 (32768B)
    unsigned short* spTp = (unsigned short*)(smem + 32768);  // [128][16] (4096B)
    float* ssL  = (float*)(smem + 36864);              // [4][16]
    float* watc = (float*)(smem + 37120);              // [4][128]

    const int tid  = threadIdx.x;
    const int w    = tid >> 6;
    const int lane = tid & 63;
    const int lrow = lane & 15, quad = lane >> 4;

    const int t0  = blockIdx.x * 16;
    const int bb  = t0 >> 12;
    const int tl0 = t0 & (T_ - 1);

    // A: lane reads its own fragment slices of row t0+lrow, K-quarter w.
    const float* gA = tokens + (size_t)(t0 + lrow)*D_ + w*256 + quad*8;
    // B: 8 fragment base pointers (cn rows, same K-quarter).
    const unsigned short* bqp[8];
    #pragma unroll
    for (int ni = 0; ni < 8; ni++)
        bqp[ni] = cn + (size_t)(ni*16 + lrow)*D_ + w*256 + quad*8;

    f32x4 acc[8];
    #pragma unroll
    for (int ni = 0; ni < 8; ni++) acc[ni] = (f32x4){0.f,0.f,0.f,0.f};

    float ss = 0.f;
    float4 Aq0[4], Aq1[4];      // depth-2 A queue (A(s), A(s+1))
    bf16x8 Bq[8];               // B(s, kk0) prefetched

    // prologue
    #pragma unroll
    for (int j = 0; j < 2; j++){
        Aq0[j]   = *(const float4*)(gA + j*4);
        Aq0[2+j] = *(const float4*)(gA + 32 + j*4);
        Aq1[j]   = *(const float4*)(gA + 64 + j*4);
        Aq1[2+j] = *(const float4*)(gA + 64 + 32 + j*4);
    }
    #pragma unroll
    for (int ni = 0; ni < 8; ni++)
        Bq[ni] = *(const bf16x8*)(bqp[ni]);

    #pragma unroll
    for (int s = 0; s < 4; s++){
        const int kof = s*64;
        // B(s, kk1)
        bf16x8 Bn[8];
        #pragma unroll
        for (int ni = 0; ni < 8; ni++)
            Bn[ni] = *(const bf16x8*)(bqp[ni] + kof + 32);
        // A(s+2)
        float4 An[4];
        if (s + 2 < 4){
            #pragma unroll
            for (int j = 0; j < 2; j++){
                An[j]   = *(const float4*)(gA + (s+2)*64 + j*4);
                An[2+j] = *(const float4*)(gA + (s+2)*64 + 32 + j*4);
            }
        }
        // B(s+1, kk0)
        bf16x8 B2[8];
        if (s + 1 < 4){
            #pragma unroll
            for (int ni = 0; ni < 8; ni++)
                B2[ni] = *(const bf16x8*)(bqp[ni] + kof + 64);
        }
        // consume A(s)
        float4 a0 = Aq0[0], a1 = Aq0[1], a2 = Aq0[2], a3 = Aq0[3];
        ss += a0.x*a0.x + a0.y*a0.y + a0.z*a0.z + a0.w*a0.w
            + a1.x*a1.x + a1.y*a1.y + a1.z*a1.z + a1.w*a1.w
            + a2.x*a2.x + a2.y*a2.y + a2.z*a2.z + a2.w*a2.w
            + a3.x*a3.x + a3.y*a3.y + a3.z*a3.z + a3.w*a3.w;
        bf16x8 af0 = pk(a0, a1);
        bf16x8 af1 = pk(a2, a3);

        __builtin_amdgcn_s_setprio(1);
        #pragma unroll
        for (int ni = 0; ni < 8; ni++)
            acc[ni] = __builtin_amdgcn_mfma_f32_16x16x32_bf16(af0, Bq[ni], acc[ni], 0, 0, 0);
        #pragma unroll
        for (int ni = 0; ni < 8; ni++)
            acc[ni] = __builtin_amdgcn_mfma_f32_16x16x32_bf16(af1, Bn[ni], acc[ni], 0, 0, 0);
        __builtin_amdgcn_s_setprio(0);

        #pragma unroll
        for (int j = 0; j < 4; j++){ Aq0[j] = Aq1[j]; Aq1[j] = An[j]; }
        #pragma unroll
        for (int ni = 0; ni < 8; ni++) Bq[ni] = B2[ni];
    }

    // ---- epilogue: combine K-quarters, softmax, outputs ----
    // per-row norm partial (this wave's K-quarter): reduce over quad lanes
    ss += __shfl_xor(ss, 16);
    ss += __shfl_xor(ss, 32);
    if (quad == 0) ssL[w*16 + lrow] = ss;

    // dump partial C: lane holds rows quad*4+rr, cols ni*16+lrow
    #pragma unroll
    for (int ni = 0; ni < 8; ni++){
        #pragma unroll
        for (int rr = 0; rr < 4; rr++){
            const int row = quad*4 + rr;
            simp[(w*16 + row)*128 + ni*16 + lrow] = acc[ni][rr];
        }
    }
    __syncthreads();

    // wave w handles rows 4w..4w+3; lane covers cols lane, lane+64
    float wp0 = 0.f, wp1 = 0.f;
    #pragma unroll
    for (int rr = 0; rr < 4; rr++){
        const int r = 4*w + rr;
        const float nsq = ssL[r] + ssL[16 + r] + ssL[32 + r] + ssL[48 + r];
        const float sc  = 10.0f / fmaxf(sqrtf(nsq), 1e-12f);
        const int c0 = lane, c1 = lane + 64;
        float v0 = (simp[r*128 + c0] + simp[(16 + r)*128 + c0]
                  + simp[(32 + r)*128 + c0] + simp[(48 + r)*128 + c0]) * sc;
        float v1 = (simp[r*128 + c1] + simp[(16 + r)*128 + c1]
                  + simp[(32 + r)*128 + c1] + simp[(48 + r)*128 + c1]) * sc;
        float m = v0;                         // c0 < 64 < E_ always valid
        if (c1 < E_) m = fmaxf(m, v1);
        #pragma unroll
        for (int off = 1; off < 64; off <<= 1) m = fmaxf(m, __shfl_xor(m, off));
        float e0 = __expf(v0 - m);
        float e1 = (c1 < E_) ? __expf(v1 - m) : 0.f;
        float sum = e0 + e1;
        #pragma unroll
        for (int off = 1; off < 64; off <<= 1) sum += __shfl_xor(sum, off);
        const float rinv = 1.0f / sum;
        const float p0 = e0 * rinv;
        const float p1 = e1 * rinv;
        out_assign[(size_t)(t0 + r)*E_ + c0] = p0;           // coalesced 256B
        if (c1 < E_) out_assign[(size_t)(t0 + r)*E_ + c1] = p1;
        wp0 += p0; wp1 += p1;
        spTp[c0*16 + r] = f2b(p0);
        spTp[c1*16 + r] = f2b(p1);
    }
    watc[w*128 + lane]      = wp0;
    watc[w*128 + 64 + lane] = wp1;
    __syncthreads();

    if (tid < 128)
        wpart[((size_t)bb*256 + (tl0 >> 4))*EP_ + tid] =
            watc[tid] + watc[128 + tid] + watc[256 + tid] + watc[384 + tid];

    // pT store: thread -> (e = tid>>1, 8-half piece)
    {
        const int e = tid >> 1;
        const int o = (tid & 1) * 8;
        uint4 v = *(const uint4*)(spTp + e*16 + o);
        *(uint4*)(pT + ((size_t)bb*EP_ + e)*T_ + tl0 + o) = v;
    }
}

// ---------------- K3: partial entity_features (64e x 64d tiles) ----------------
// grid = (32 = 16 d-tiles x 2 e-tiles, TC_ t-chunks, 8 batches) = 2048 blocks.
// LDS 32KB -> 5 blocks/CU (20 waves/CU, was 12). Dbuf, 1 barrier/chunk.
__global__ __launch_bounds__(256) void k_feat(const float* __restrict__ tokens,
                                              const unsigned short* __restrict__ pT,
                                              float* __restrict__ facc_part){
    const int tid = threadIdx.x;
    const int d0  = (blockIdx.x & 15) * 64;
    const int e0  = (blockIdx.x >> 4) * 64;
    const int tc  = blockIdx.y;
    const int bb  = blockIdx.z;

    __shared__ __align__(16) unsigned short lds_a[2][64*64];    // 2 x 8KB  [e][t]
    __shared__ __align__(16) unsigned short lds_b[2][64*64];    // 2 x 8KB  [d][t]

    const int lane = tid & 63, w = tid >> 6;
    const int wm = w >> 1, wn = w & 1, lrow = lane & 15, quad = lane >> 4;

    // A DMA: wave w fills chunks c=2w..2w+1 (8 rows each), swizzled source.
    const unsigned short* gA[2];
    int lAoff[2];
    #pragma unroll
    for (int j = 0; j < 2; j++){
        int c = 2*w + j;
        int brow = 8*c + (lane >> 3);                  // local row 0..63
        int bjg  = (lane & 7) ^ (brow & 7);
        gA[j] = pT + ((size_t)bb*EP_ + e0 + brow)*T_ + tc*KT_ + bjg*8;
        lAoff[j] = c*512;
    }

    // B: thread owns d-column dcol (0..63) and t-octets o1, o1+4.
    const int dcol = tid & 63;
    const int o1 = tid >> 6;            // 0..3
    const float* gB = tokens + ((size_t)bb*T_ + (size_t)tc*KT_)*D_ + d0 + dcol;
    const int s1 = o1 ^ (dcol & 7), s2 = (o1 + 4) ^ (dcol & 7);
    const int b1off = dcol*64 + s1*8;
    const int b2off = dcol*64 + s2*8;

    f32x4 acc[2][2];
    #pragma unroll
    for (int i = 0; i < 2; i++)
        #pragma unroll
        for (int j = 0; j < 2; j++) acc[i][j] = (f32x4){0.f,0.f,0.f,0.f};

    // prologue: chunk 0
    float b1[8], b2[8];
    #pragma unroll
    for (int tt = 0; tt < 8; tt++) b1[tt] = gB[(size_t)(o1*8 + tt)*D_];
    #pragma unroll
    for (int tt = 0; tt < 8; tt++) b2[tt] = gB[(size_t)((o1+4)*8 + tt)*D_];
    #pragma unroll
    for (int j = 0; j < 2; j++) dma16(gA[j], &lds_a[0][lAoff[j]]);
    *(uint4*)(&lds_b[0][b1off]) = pack8(make_float4(b1[0],b1[1],b1[2],b1[3]),
                                        make_float4(b1[4],b1[5],b1[6],b1[7]));
    *(uint4*)(&lds_b[0][b2off]) = pack8(make_float4(b2[0],b2[1],b2[2],b2[3]),
                                        make_float4(b2[4],b2[5],b2[6],b2[7]));

    for (int ki = 0; ki < 8; ki++){
        const int cur = ki & 1;
        __syncthreads();                       // buffers[cur] ready
        if (ki < 7){
            const int kt0 = (ki + 1) * 64;
            #pragma unroll
            for (int tt = 0; tt < 8; tt++) b1[tt] = gB[(size_t)(kt0 + o1*8 + tt)*D_];
            #pragma unroll
            for (int tt = 0; tt < 8; tt++) b2[tt] = gB[(size_t)(kt0 + (o1+4)*8 + tt)*D_];
            #pragma unroll
            for (int j = 0; j < 2; j++) dma16(gA[j] + kt0, &lds_a[1-cur][lAoff[j]]);
        }
        const unsigned short* aC = &lds_a[cur][0];
        const unsigned short* bC = &lds_b[cur][0];
        #pragma unroll
        for (int kk = 0; kk < 2; kk++){
            const int b = quad + 4*kk;
            bf16x8 af[2], bfr[2];
            #pragma unroll
            for (int mi = 0; mi < 2; mi++){
                const int e = wm*32 + mi*16 + lrow;
                af[mi] = *(const bf16x8*)(aC + e*64 + ((b ^ (e & 7)) * 8));
            }
            #pragma unroll
            for (int ni = 0; ni < 2; ni++){
                const int d = wn*32 + ni*16 + lrow;
                bfr[ni] = *(const bf16x8*)(bC + d*64 + ((b ^ (d & 7)) * 8));
            }
            #pragma unroll
            for (int mi = 0; mi < 2; mi++)
                #pragma unroll
                for (int ni = 0; ni < 2; ni++)
                    acc[mi][ni] = __builtin_amdgcn_mfma_f32_16x16x32_bf16(af[mi], bfr[ni], acc[mi][ni], 0, 0, 0);
        }
        if (ki < 7){
            *(uint4*)(&lds_b[1-cur][b1off]) = pack8(make_float4(b1[0],b1[1],b1[2],b1[3]),
                                                    make_float4(b1[4],b1[5],b1[6],b1[7]));
            *(uint4*)(&lds_b[1-cur][b2off]) = pack8(make_float4(b2[0],b2[1],b2[2],b2[3]),
                                                    make_float4(b2[4],b2[5],b2[6],b2[7]));
        }
    }

    #pragma unroll
    for (int mi = 0; mi < 2; mi++){
        #pragma unroll
        for (int ni = 0; ni < 2; ni++){
            int d = d0 + wn*32 + ni*16 + lrow;
            #pragma unroll
            for (int rr = 0; rr < 4; rr++){
                int e = e0 + wm*32 + mi*16 + quad*4 + rr;
                if (e < E_)
                    facc_part[((size_t)(tc*B_ + bb)*E_ + e)*D_ + d] = acc[mi][ni][rr];
            }
        }
    }
}

// ---------------- K4: w = sum chunks; out = (sum parts)/(w+eps) ----------------
// grid = (E_, B_), 256 threads. wpart has 256 chunks of 16 tokens.
__global__ __launch_bounds__(256) void k_final(const float* __restrict__ wpart,
                                               const float* __restrict__ facc_part,
                                               float* __restrict__ out_feat){
    const int e  = blockIdx.x;
    const int bb = blockIdx.y;
    const int tid = threadIdx.x;

    __shared__ float red[256];
    red[tid] = wpart[((size_t)bb*256 + tid)*EP_ + e];
    __syncthreads();
    for (int st = 128; st > 0; st >>= 1){ if (tid < st) red[tid] += red[tid+st]; __syncthreads(); }
    const float winv = 1.0f / (red[0] + 1e-6f);

    const int d = tid * 4;
    float4 o = make_float4(0.f, 0.f, 0.f, 0.f);
    #pragma unroll
    for (int tc = 0; tc < TC_; tc++){
        float4 p = *(const float4*)(facc_part + ((size_t)(tc*B_ + bb)*E_ + e)*D_ + d);
        o.x += p.x; o.y += p.y; o.z += p.z; o.w += p.w;
    }
    o.x *= winv; o.y *= winv; o.z *= winv; o.w *= winv;
    *(float4*)(out_feat + ((size_t)bb*E_ + e)*D_ + d) = o;
}

extern "C" void kernel_launch(void* const* d_in, const int* in_sizes, int n_in,
                              void* d_out, int out_size, void* d_ws, size_t ws_size,
                              hipStream_t stream){
    const float* tokens = (const float*)d_in[0];
    const float* cent   = (const float*)d_in[1];
    float* out        = (float*)d_out;
    float* out_assign = out;
    float* out_feat   = out + (size_t)B_*T_*E_;

    float* wpart = (float*)d_ws;                                      // B*256*128 f32
    float* facc_part = wpart + (size_t)B_*256*EP_;                    // TC_*B*E*D f32
    unsigned short* cn = (unsigned short*)(facc_part + (size_t)TC_*B_*E_*D_);  // EP_*D_ bf16
    unsigned short* pT = cn + (size_t)EP_*D_;                         // B_*EP_*T_ bf16

    k_cnorm<<<EP_, 256, 0, stream>>>(cent, cn);
    k_sim  <<<NTOK/16, 256, 0, stream>>>(tokens, cn, out_assign, pT, wpart);
    k_feat <<<dim3(32, TC_, B_), 256, 0, stream>>>(tokens, pT, facc_part);
    k_final<<<dim3(E_, B_), 256, 0, stream>>>(wpart, facc_part, out_feat);
}